// Round 1
// baseline (1835.515 us; speedup 1.0000x reference)
//
#include <hip/hip_runtime.h>
#include <math.h>

#define NN 50000
#define NE 512000
#define NE2 256000
#define SCALE 0.17677669529663687f   // 1/sqrt(32)
#define EPSV 1e-5f

// ---- workspace layout (float offsets) ----
#define OFF_Q      0UL
#define OFF_K      6400000UL
#define OFF_V      12800000UL
#define OFF_EX1    19200000UL
#define OFF_EX2    21248000UL
#define OFF_XH     23296000UL
#define OFF_ATTR   31488000UL
#define OFF_O1     33088000UL
#define OFF_XGAT   34688000UL
#define OFF_S1     36288000UL   // zero-region start
#define OFF_S2     36488000UL
#define OFF_AGG    36688000UL
#define OFF_DEGB   43088000UL
#define OFF_O1ACC  43138000UL
#define OFF_STATS  44738000UL
#define ZERO_START OFF_S1
#define ZERO_COUNT (44738064UL - OFF_S1)   // floats

// ---------------- K1: q,k,v = x @ W{q,k,v} + b ----------------
__global__ void qkv_kernel(const float* __restrict__ x,
                           const float* __restrict__ Wq, const float* __restrict__ bq,
                           const float* __restrict__ Wk, const float* __restrict__ bk,
                           const float* __restrict__ Wv, const float* __restrict__ bv,
                           float* __restrict__ q, float* __restrict__ k, float* __restrict__ v) {
    __shared__ float xs[8 * 128];
    const int tid = threadIdx.x;
    const int j = tid & 127;
    const int g = tid >> 7;
    const size_t n0 = (size_t)blockIdx.x * 8;
    ((float4*)xs)[tid] = ((const float4*)(x + n0 * 128))[tid];
    __syncthreads();
    float aq[4] = {0,0,0,0}, ak[4] = {0,0,0,0}, av[4] = {0,0,0,0};
    #pragma unroll 4
    for (int d = 0; d < 128; d++) {
        const float wq = Wq[d*128 + j];
        const float wk = Wk[d*128 + j];
        const float wv = Wv[d*128 + j];
        #pragma unroll
        for (int r = 0; r < 4; r++) {
            const float xv = xs[(g + 2*r)*128 + d];
            aq[r] += xv * wq; ak[r] += xv * wk; av[r] += xv * wv;
        }
    }
    const float bqv = bq[j], bkv = bk[j], bvv = bv[j];
    #pragma unroll
    for (int r = 0; r < 4; r++) {
        const size_t n = n0 + g + 2*r;
        q[n*128 + j] = aq[r] + bqv;
        k[n*128 + j] = ak[r] + bkv;
        v[n*128 + j] = av[r] + bvv;
    }
}

// ---------------- K2: per-edge logits -> exp, segment sums ----------------
// ea2[e,:] = edge_attr[e,:] @ We2 + be2 (We2 column j register-cached per thread)
// ex1[e,h] = exp(scale * dot(q[dst,h], k[src,h])), ex2 likewise vs ea2
__global__ __launch_bounds__(128, 2)
void edge_pass1(const float* __restrict__ ea, const int* __restrict__ eidx,
                const float* __restrict__ q, const float* __restrict__ k,
                const float* __restrict__ We2, const float* __restrict__ be2,
                float* __restrict__ ex1, float* __restrict__ ex2,
                float* __restrict__ s1, float* __restrict__ s2) {
    __shared__ float eas[8 * 128];
    const int j = threadIdx.x;
    float wc[128];
    #pragma unroll
    for (int d = 0; d < 128; d++) wc[d] = We2[d*128 + j];
    const float bj = be2[j];
    const int h = j >> 5;
    float4* eas4 = (float4*)eas;
    for (size_t e0 = (size_t)blockIdx.x * 8; e0 < NE; e0 += (size_t)gridDim.x * 8) {
        const float4* g4 = (const float4*)(ea + e0 * 128);
        eas4[j] = g4[j];
        eas4[j + 128] = g4[j + 128];
        __syncthreads();
        for (int ei = 0; ei < 8; ei++) {
            const size_t e = e0 + ei;
            const int src = eidx[e];
            const int dst = eidx[NE + e];
            const float qv = q[(size_t)dst*128 + j];
            const float kv = k[(size_t)src*128 + j];
            float a0 = 0.f, a1 = 0.f, a2 = 0.f, a3 = 0.f;
            #pragma unroll
            for (int i = 0; i < 32; i++) {
                const float4 e4 = eas4[ei*32 + i];
                a0 += e4.x * wc[4*i+0];
                a1 += e4.y * wc[4*i+1];
                a2 += e4.z * wc[4*i+2];
                a3 += e4.w * wc[4*i+3];
            }
            const float ea2v = (a0 + a1) + (a2 + a3) + bj;
            float p1 = qv * kv;
            float p2 = qv * ea2v;
            #pragma unroll
            for (int off = 16; off > 0; off >>= 1) {
                p1 += __shfl_down(p1, off, 32);
                p2 += __shfl_down(p2, off, 32);
            }
            if ((j & 31) == 0) {
                const float v1 = expf(p1 * SCALE);
                const float v2 = expf(p2 * SCALE);
                ex1[e*4 + h] = v1;
                ex2[e*4 + h] = v2;
                atomicAdd(&s1[(size_t)dst*4 + h], v1);
                atomicAdd(&s2[(size_t)dst*4 + h], v2);
            }
        }
        __syncthreads();
    }
}

// ---------------- K3: per-edge message -> agg[dst, 128] ----------------
__global__ __launch_bounds__(128, 2)
void edge_pass2(const float* __restrict__ ea, const int* __restrict__ eidx,
                const float* __restrict__ v,
                const float* __restrict__ We3, const float* __restrict__ be3,
                const float* __restrict__ ex1, const float* __restrict__ ex2,
                const float* __restrict__ s1, const float* __restrict__ s2,
                float* __restrict__ agg) {
    __shared__ float eas[8 * 128];
    const int j = threadIdx.x;
    float wc[128];
    #pragma unroll
    for (int d = 0; d < 128; d++) wc[d] = We3[d*128 + j];
    const float bj = be3[j];
    const int h = j >> 5;
    float4* eas4 = (float4*)eas;
    for (size_t e0 = (size_t)blockIdx.x * 8; e0 < NE; e0 += (size_t)gridDim.x * 8) {
        const float4* g4 = (const float4*)(ea + e0 * 128);
        eas4[j] = g4[j];
        eas4[j + 128] = g4[j + 128];
        __syncthreads();
        for (int ei = 0; ei < 8; ei++) {
            const size_t e = e0 + ei;
            const int src = eidx[e];
            const int dst = eidx[NE + e];
            const float a1w = ex1[e*4 + h] / (s1[(size_t)dst*4 + h] + 1e-16f);
            const float a2w = ex2[e*4 + h] / (s2[(size_t)dst*4 + h] + 1e-16f);
            const float vv = v[(size_t)src*128 + j];
            float a0 = 0.f, b1 = 0.f, b2 = 0.f, b3 = 0.f;
            #pragma unroll
            for (int i = 0; i < 32; i++) {
                const float4 e4 = eas4[ei*32 + i];
                a0 += e4.x * wc[4*i+0];
                b1 += e4.y * wc[4*i+1];
                b2 += e4.z * wc[4*i+2];
                b3 += e4.w * wc[4*i+3];
            }
            const float ea3v = (a0 + b1) + (b2 + b3) + bj;
            atomicAdd(&agg[(size_t)dst*128 + j], a1w * vv + a2w * ea3v);
        }
        __syncthreads();
    }
}

// ---------------- generic (M x 128) @ (128 x 32) ----------------
__global__ void gemm_d128_o32(const float* __restrict__ A, const float* __restrict__ W,
                              float* __restrict__ out) {
    __shared__ float as[8 * 128];
    const int tid = threadIdx.x;
    const int p = tid & 31;
    const int mm = tid >> 5;
    const size_t m0 = (size_t)blockIdx.x * 8;
    ((float4*)as)[tid] = ((const float4*)(A + m0 * 128))[tid];
    __syncthreads();
    float c0 = 0.f, c1 = 0.f, c2 = 0.f, c3 = 0.f;
    const float4* as4 = (const float4*)as;
    #pragma unroll 8
    for (int i = 0; i < 32; i++) {
        const float4 a4 = as4[mm*32 + i];
        c0 += a4.x * W[(4*i+0)*32 + p];
        c1 += a4.y * W[(4*i+1)*32 + p];
        c2 += a4.z * W[(4*i+2)*32 + p];
        c3 += a4.w * W[(4*i+3)*32 + p];
    }
    out[(m0 + mm)*32 + p] = (c0 + c1) + (c2 + c3);
}

// ---------------- BN stats ----------------
__global__ void bn_stats(const float* __restrict__ xg, float* __restrict__ stats) {
    __shared__ float ls[256], lss[256];
    const int tid = threadIdx.x;
    float s = 0.f, ss = 0.f;
    for (size_t i = (size_t)blockIdx.x*256 + tid; i < (size_t)NN*32; i += (size_t)gridDim.x*256) {
        const float val = xg[i];
        s += val; ss += val * val;
    }
    ls[tid] = s; lss[tid] = ss;
    __syncthreads();
    if (tid < 32) {
        float as_ = 0.f, ass = 0.f;
        #pragma unroll
        for (int w = 0; w < 8; w++) { as_ += ls[tid + 32*w]; ass += lss[tid + 32*w]; }
        atomicAdd(&stats[tid], as_);
        atomicAdd(&stats[32 + tid], ass);
    }
}

// ---------------- BN apply + exact GELU ----------------
__global__ void bn_gelu(const float* __restrict__ xg, const float* __restrict__ stats,
                        const float* __restrict__ bnw, const float* __restrict__ bnb,
                        float* __restrict__ out) {
    const size_t i = (size_t)blockIdx.x * 256 + threadIdx.x;
    const int c = i & 31;
    const float mu = stats[c] * (1.0f / NN);
    const float var = stats[32 + c] * (1.0f / NN) - mu * mu;
    const float xn = bnw[c] * (xg[i] - mu) * rsqrtf(var + EPSV) + bnb[c];
    out[i] = 0.5f * xn * (1.0f + erff(xn * 0.70710678118654752f));
}

// ---------------- hypergraph scatter: o1acc, degb ----------------
__global__ void hyper_scatter(const float* __restrict__ xh, const int* __restrict__ eidx,
                              float* __restrict__ o1acc, float* __restrict__ degb) {
    const int tid = threadIdx.x;
    const int c = tid & 31;
    const size_t i = (size_t)blockIdx.x * 8 + (tid >> 5);
    const int src = eidx[i];
    const int dst = eidx[NE + i];
    const float xv = xh[i*32 + c];
    atomicAdd(&o1acc[(size_t)src*32 + c], xv);
    atomicAdd(&o1acc[(size_t)dst*32 + c], xv);
    if (c == 0) {
        atomicAdd(&degb[src], 1.0f);
        atomicAdd(&degb[dst], 1.0f);
    }
}

// ---------------- o1 = Binv * o1acc + attr ----------------
__global__ void o1_finalize(const float* __restrict__ o1acc, const float* __restrict__ degb,
                            const float* __restrict__ attr, float* __restrict__ o1) {
    const size_t i = (size_t)blockIdx.x * 256 + threadIdx.x;
    const int n = (int)(i >> 5);
    const float d = degb[n];
    const float binv = d > 0.f ? 1.0f / d : 0.0f;
    o1[i] = o1acc[i] * binv + attr[i];
}

// ---------------- edge_attr2 = 0.5*(o1[src]+o1[dst]) + bh ----------------
__global__ void edge_out(const float* __restrict__ o1, const int* __restrict__ eidx,
                         const float* __restrict__ bh, float* __restrict__ out2) {
    const size_t idx = (size_t)blockIdx.x * 256 + threadIdx.x;
    const size_t i = idx >> 5;
    const int c = (int)(idx & 31);
    const int src = eidx[i];
    const int dst = eidx[NE + i];
    out2[idx] = 0.5f * (o1[(size_t)src*32 + c] + o1[(size_t)dst*32 + c]) + bh[c];
}

extern "C" void kernel_launch(void* const* d_in, const int* in_sizes, int n_in,
                              void* d_out, int out_size, void* d_ws, size_t ws_size,
                              hipStream_t stream) {
    const float* x    = (const float*)d_in[0];
    const float* eatt = (const float*)d_in[1];
    const float* Wq   = (const float*)d_in[2];
    const float* bq   = (const float*)d_in[3];
    const float* Wk   = (const float*)d_in[4];
    const float* bk   = (const float*)d_in[5];
    const float* Wv   = (const float*)d_in[6];
    const float* bv   = (const float*)d_in[7];
    const float* We2  = (const float*)d_in[8];
    const float* be2  = (const float*)d_in[9];
    const float* We3  = (const float*)d_in[10];
    const float* be3  = (const float*)d_in[11];
    const float* Wcon = (const float*)d_in[12];
    const float* bnw  = (const float*)d_in[13];
    const float* bnb  = (const float*)d_in[14];
    const float* Wh1  = (const float*)d_in[15];
    const float* Wh2  = (const float*)d_in[16];
    const float* bh   = (const float*)d_in[17];
    const int*   eidx = (const int*)d_in[18];

    float* ws    = (float*)d_ws;
    float* q     = ws + OFF_Q;
    float* k     = ws + OFF_K;
    float* v     = ws + OFF_V;
    float* ex1   = ws + OFF_EX1;
    float* ex2   = ws + OFF_EX2;
    float* xh    = ws + OFF_XH;
    float* attr  = ws + OFF_ATTR;
    float* o1    = ws + OFF_O1;
    float* xgat  = ws + OFF_XGAT;
    float* s1    = ws + OFF_S1;
    float* s2    = ws + OFF_S2;
    float* agg   = ws + OFF_AGG;
    float* degb  = ws + OFF_DEGB;
    float* o1acc = ws + OFF_O1ACC;
    float* stats = ws + OFF_STATS;
    float* out0  = (float*)d_out;
    float* out1  = (float*)d_out + (size_t)NN * 32;

    hipMemsetAsync(ws + ZERO_START, 0, ZERO_COUNT * sizeof(float), stream);

    qkv_kernel<<<6250, 256, 0, stream>>>(x, Wq, bq, Wk, bk, Wv, bv, q, k, v);
    edge_pass1<<<2048, 128, 0, stream>>>(eatt, eidx, q, k, We2, be2, ex1, ex2, s1, s2);
    edge_pass2<<<2048, 128, 0, stream>>>(eatt, eidx, v, We3, be3, ex1, ex2, s1, s2, agg);
    gemm_d128_o32<<<6250, 256, 0, stream>>>(agg, Wcon, xgat);
    bn_stats<<<256, 256, 0, stream>>>(xgat, stats);
    bn_gelu<<<6250, 256, 0, stream>>>(xgat, stats, bnw, bnb, out0);

    gemm_d128_o32<<<32000, 256, 0, stream>>>(eatt, Wh1, xh);
    gemm_d128_o32<<<6250, 256, 0, stream>>>(x, Wh2, attr);
    hyper_scatter<<<32000, 256, 0, stream>>>(xh, eidx, o1acc, degb);
    o1_finalize<<<6250, 256, 0, stream>>>(o1acc, degb, attr, o1);
    edge_out<<<32000, 256, 0, stream>>>(o1, eidx, bh, out1);
}

// Round 2
// 1290.528 us; speedup vs baseline: 1.4223x; 1.4223x over previous
//
#include <hip/hip_runtime.h>
#include <math.h>

#define NN 50000
#define NE 512000
#define NE2 256000
#define SCALE 0.17677669529663687f   // 1/sqrt(32)
#define EPSV 1e-5f
#define CHUNK 128000                 // edges per GEMM/pass chunk (4 chunks)

// ---- workspace layout (float offsets) ----
// region1 (dead after pass2, then aliased):
#define OFF_Q      0UL          // 50000*128
#define OFF_K      6400000UL
#define OFF_V      12800000UL
//   aliases (used after pass2):
#define OFF_ATTR   0UL          // 50000*32
#define OFF_O1     1600000UL
#define OFF_XGAT   3200000UL
#define OFF_O1ACC  4800000UL
#define OFF_DEGB   6400000UL    // 50000
#define OFF_STATS  6450000UL    // 64
// region2:
#define OFF_EX1    19200000UL   // 512000*4
#define OFF_EX2    21248000UL
#define OFF_CC     23296000UL   // bf16 chunk buffer: 128000*128*2B = 8.192M floats
#define OFF_S1     31488000UL   // 50000*4   (zero region start)
#define OFF_S2     31688000UL
//   alias: xh = region2 start (256000*32 floats = 8.192M)
#define OFF_XH     19200000UL
// region3:
#define OFF_AGG    31888000UL   // 50000*128  (zero region end = 38288000)
// region4:
#define OFF_WBT    38288000UL   // bf16 256*128 = 16384 floats
#define OFF_BIASB  38304384UL   // 256 floats
// total: 38304640 floats = 153.2 MB

typedef __attribute__((ext_vector_type(8))) short bf16x8;
typedef __attribute__((ext_vector_type(8))) unsigned short us8;
typedef __attribute__((ext_vector_type(4))) float f32x4;

__device__ __forceinline__ unsigned short f2bf(float f) {
    unsigned int u = __float_as_uint(f);
    unsigned int r = (u + 0x7FFFu + ((u >> 16) & 1u)) >> 16;
    return (unsigned short)r;
}
__device__ __forceinline__ float bf2f(unsigned short u) {
    return __uint_as_float(((unsigned int)u) << 16);
}

// ---------------- pack WbT (transposed, bf16) + biasb ----------------
// WbT[j][k] = (j<128 ? We2 : We3)[k][j%128], j=0..255, k=0..127
__global__ void pack_w(const float* __restrict__ We2, const float* __restrict__ be2,
                       const float* __restrict__ We3, const float* __restrict__ be3,
                       unsigned short* __restrict__ WbT, float* __restrict__ biasb) {
    const int idx = blockIdx.x * 256 + threadIdx.x;
    if (idx < 32768) {
        const int j = idx >> 7;
        const int k = idx & 127;
        const float w = (j < 128) ? We2[k * 128 + j] : We3[k * 128 + (j - 128)];
        WbT[idx] = f2bf(w);
    } else if (idx < 33024) {
        const int jj = idx - 32768;
        biasb[jj] = (jj < 128) ? be2[jj] : be3[jj - 128];
    }
}

// ---------------- MFMA GEMM: Cc = bf16(A_chunk(128000x128 fp32) @ W_half + bias) ----------------
// block = 256 threads (4 waves), tile 128(M) x 128(N), K=128 staged in 2 halves of 64
__global__ __launch_bounds__(256)
void gemm_ea(const float* __restrict__ A, const unsigned short* __restrict__ WbT,
             const float* __restrict__ biasb, unsigned short* __restrict__ Cc, int half) {
    __shared__ unsigned short As[128 * 72];   // stride 72 bf16 (144B, 16B-aligned rows)
    __shared__ unsigned short Bs[128 * 72];   // Bs[n][k_local]
    const int tid = threadIdx.x;
    const int wave = tid >> 6;
    const int lane = tid & 63;
    const int quad = lane >> 4;
    const int l16 = lane & 15;
    const int m0 = (wave & 1) * 64;
    const int n0 = (wave >> 1) * 64;
    const size_t r0 = (size_t)blockIdx.x * 128;

    f32x4 acc[4][4];
    #pragma unroll
    for (int i = 0; i < 4; i++)
        #pragma unroll
        for (int j = 0; j < 4; j++) acc[i][j] = (f32x4){0.f, 0.f, 0.f, 0.f};

    for (int kh = 0; kh < 2; kh++) {
        // stage A half: 128 rows x 64 cols fp32 -> bf16
        #pragma unroll
        for (int i = 0; i < 8; i++) {
            const int q = tid + 256 * i;
            const int row = q >> 4;
            const int c4 = q & 15;
            const float4 a4 = *(const float4*)(A + (r0 + row) * 128 + kh * 64 + c4 * 4);
            ushort4 b4;
            b4.x = f2bf(a4.x); b4.y = f2bf(a4.y); b4.z = f2bf(a4.z); b4.w = f2bf(a4.w);
            *(ushort4*)(&As[row * 72 + c4 * 4]) = b4;
        }
        // stage B half: Bs[n][k] from WbT[(half*128+n)*128 + kh*64 + k]
        {
            const int n = tid >> 1;
            const int koff = (tid & 1) * 32;
            const unsigned short* src = WbT + (size_t)(half * 128 + n) * 128 + kh * 64 + koff;
            #pragma unroll
            for (int u = 0; u < 4; u++) {
                *(us8*)(&Bs[n * 72 + koff + 8 * u]) = *(const us8*)(src + 8 * u);
            }
        }
        __syncthreads();
        #pragma unroll
        for (int kc = 0; kc < 64; kc += 32) {
            bf16x8 af[4], bf[4];
            #pragma unroll
            for (int i = 0; i < 4; i++)
                af[i] = *(const bf16x8*)(&As[(m0 + 16 * i + l16) * 72 + kc + quad * 8]);
            #pragma unroll
            for (int j = 0; j < 4; j++)
                bf[j] = *(const bf16x8*)(&Bs[(n0 + 16 * j + l16) * 72 + kc + quad * 8]);
            #pragma unroll
            for (int i = 0; i < 4; i++)
                #pragma unroll
                for (int j = 0; j < 4; j++)
                    acc[i][j] = __builtin_amdgcn_mfma_f32_16x16x32_bf16(af[i], bf[j], acc[i][j], 0, 0, 0);
        }
        __syncthreads();
    }
    // epilogue: add bias (fp32), cast bf16, store
    #pragma unroll
    for (int j = 0; j < 4; j++) {
        const int col = n0 + 16 * j + l16;
        const float bcol = biasb[half * 128 + col];
        #pragma unroll
        for (int i = 0; i < 4; i++) {
            #pragma unroll
            for (int r = 0; r < 4; r++) {
                const int row = m0 + 16 * i + quad * 4 + r;
                Cc[(r0 + row) * 128 + col] = f2bf(acc[i][j][r] + bcol);
            }
        }
    }
}

// ---------------- K1: q,k,v = x @ W{q,k,v} + b ----------------
__global__ void qkv_kernel(const float* __restrict__ x,
                           const float* __restrict__ Wq, const float* __restrict__ bq,
                           const float* __restrict__ Wk, const float* __restrict__ bk,
                           const float* __restrict__ Wv, const float* __restrict__ bv,
                           float* __restrict__ q, float* __restrict__ k, float* __restrict__ v) {
    __shared__ float xs[8 * 128];
    const int tid = threadIdx.x;
    const int j = tid & 127;
    const int g = tid >> 7;
    const size_t n0 = (size_t)blockIdx.x * 8;
    ((float4*)xs)[tid] = ((const float4*)(x + n0 * 128))[tid];
    __syncthreads();
    float aq[4] = {0,0,0,0}, ak[4] = {0,0,0,0}, av[4] = {0,0,0,0};
    #pragma unroll 4
    for (int d = 0; d < 128; d++) {
        const float wq = Wq[d*128 + j];
        const float wk = Wk[d*128 + j];
        const float wv = Wv[d*128 + j];
        #pragma unroll
        for (int r = 0; r < 4; r++) {
            const float xv = xs[(g + 2*r)*128 + d];
            aq[r] += xv * wq; ak[r] += xv * wk; av[r] += xv * wv;
        }
    }
    const float bqv = bq[j], bkv = bk[j], bvv = bv[j];
    #pragma unroll
    for (int r = 0; r < 4; r++) {
        const size_t n = n0 + g + 2*r;
        q[n*128 + j] = aq[r] + bqv;
        k[n*128 + j] = ak[r] + bkv;
        v[n*128 + j] = av[r] + bvv;
    }
}

// ---------------- pass1: logits -> ex1/ex2, s1/s2 (one wave per edge) ----------------
__global__ void pass1(const int* __restrict__ eidx,
                      const float* __restrict__ q, const float* __restrict__ k,
                      const unsigned short* __restrict__ Cc, long e_base,
                      float* __restrict__ ex1, float* __restrict__ ex2,
                      float* __restrict__ s1, float* __restrict__ s2) {
    const size_t e = (size_t)e_base + blockIdx.x * 4 + (threadIdx.x >> 6);
    const int lane = threadIdx.x & 63;
    const int src = eidx[e];
    const int dst = eidx[NE + e];
    const float2 qv = ((const float2*)(q + (size_t)dst * 128))[lane];
    const float2 kv = ((const float2*)(k + (size_t)src * 128))[lane];
    const unsigned int cc = ((const unsigned int*)(Cc + (e - e_base) * 128))[lane];
    const float ea2a = bf2f((unsigned short)(cc & 0xFFFF));
    const float ea2b = bf2f((unsigned short)(cc >> 16));
    float p1 = qv.x * kv.x + qv.y * kv.y;
    float p2 = qv.x * ea2a + qv.y * ea2b;
    #pragma unroll
    for (int off = 8; off > 0; off >>= 1) {
        p1 += __shfl_down(p1, off, 16);
        p2 += __shfl_down(p2, off, 16);
    }
    if ((lane & 15) == 0) {
        const int h = lane >> 4;
        const float v1 = __expf(p1 * SCALE);
        const float v2 = __expf(p2 * SCALE);
        ex1[e * 4 + h] = v1;
        ex2[e * 4 + h] = v2;
        atomicAdd(&s1[(size_t)dst * 4 + h], v1);
        atomicAdd(&s2[(size_t)dst * 4 + h], v2);
    }
}

// ---------------- pass2: msg scatter into agg (one wave per edge) ----------------
__global__ void pass2(const int* __restrict__ eidx,
                      const float* __restrict__ v,
                      const unsigned short* __restrict__ Cc, long e_base,
                      const float* __restrict__ ex1, const float* __restrict__ ex2,
                      const float* __restrict__ s1, const float* __restrict__ s2,
                      float* __restrict__ agg) {
    const size_t e = (size_t)e_base + blockIdx.x * 4 + (threadIdx.x >> 6);
    const int lane = threadIdx.x & 63;
    const int src = eidx[e];
    const int dst = eidx[NE + e];
    float a1l = 0.f, a2l = 0.f;
    if (lane < 4) {
        a1l = ex1[e * 4 + lane] / (s1[(size_t)dst * 4 + lane] + 1e-16f);
        a2l = ex2[e * 4 + lane] / (s2[(size_t)dst * 4 + lane] + 1e-16f);
    }
    const int h1 = lane >> 5;          // head of channel lane
    const int h2 = 2 + (lane >> 5);    // head of channel lane+64
    const float a1c1 = __shfl(a1l, h1), a1c2 = __shfl(a1l, h2);
    const float a2c1 = __shfl(a2l, h1), a2c2 = __shfl(a2l, h2);
    const float vv1 = v[(size_t)src * 128 + lane];
    const float vv2 = v[(size_t)src * 128 + lane + 64];
    const float e31 = bf2f(Cc[(e - e_base) * 128 + lane]);
    const float e32 = bf2f(Cc[(e - e_base) * 128 + lane + 64]);
    atomicAdd(&agg[(size_t)dst * 128 + lane],      a1c1 * vv1 + a2c1 * e31);
    atomicAdd(&agg[(size_t)dst * 128 + lane + 64], a1c2 * vv2 + a2c2 * e32);
}

// ---------------- generic (M x 128) @ (128 x 32) ----------------
__global__ void gemm_d128_o32(const float* __restrict__ A, const float* __restrict__ W,
                              float* __restrict__ out) {
    __shared__ float as[8 * 128];
    const int tid = threadIdx.x;
    const int p = tid & 31;
    const int mm = tid >> 5;
    const size_t m0 = (size_t)blockIdx.x * 8;
    ((float4*)as)[tid] = ((const float4*)(A + m0 * 128))[tid];
    __syncthreads();
    float c0 = 0.f, c1 = 0.f, c2 = 0.f, c3 = 0.f;
    const float4* as4 = (const float4*)as;
    #pragma unroll 8
    for (int i = 0; i < 32; i++) {
        const float4 a4 = as4[mm*32 + i];
        c0 += a4.x * W[(4*i+0)*32 + p];
        c1 += a4.y * W[(4*i+1)*32 + p];
        c2 += a4.z * W[(4*i+2)*32 + p];
        c3 += a4.w * W[(4*i+3)*32 + p];
    }
    out[(m0 + mm)*32 + p] = (c0 + c1) + (c2 + c3);
}

// ---------------- BN stats ----------------
__global__ void bn_stats(const float* __restrict__ xg, float* __restrict__ stats) {
    __shared__ float ls[256], lss[256];
    const int tid = threadIdx.x;
    float s = 0.f, ss = 0.f;
    for (size_t i = (size_t)blockIdx.x*256 + tid; i < (size_t)NN*32; i += (size_t)gridDim.x*256) {
        const float val = xg[i];
        s += val; ss += val * val;
    }
    ls[tid] = s; lss[tid] = ss;
    __syncthreads();
    if (tid < 32) {
        float as_ = 0.f, ass = 0.f;
        #pragma unroll
        for (int w = 0; w < 8; w++) { as_ += ls[tid + 32*w]; ass += lss[tid + 32*w]; }
        atomicAdd(&stats[tid], as_);
        atomicAdd(&stats[32 + tid], ass);
    }
}

// ---------------- BN apply + exact GELU ----------------
__global__ void bn_gelu(const float* __restrict__ xg, const float* __restrict__ stats,
                        const float* __restrict__ bnw, const float* __restrict__ bnb,
                        float* __restrict__ out) {
    const size_t i = (size_t)blockIdx.x * 256 + threadIdx.x;
    const int c = i & 31;
    const float mu = stats[c] * (1.0f / NN);
    const float var = stats[32 + c] * (1.0f / NN) - mu * mu;
    const float xn = bnw[c] * (xg[i] - mu) * rsqrtf(var + EPSV) + bnb[c];
    out[i] = 0.5f * xn * (1.0f + erff(xn * 0.70710678118654752f));
}

// ---------------- hypergraph scatter ----------------
__global__ void hyper_scatter(const float* __restrict__ xh, const int* __restrict__ eidx,
                              float* __restrict__ o1acc, float* __restrict__ degb) {
    const int tid = threadIdx.x;
    const int c = tid & 31;
    const size_t i = (size_t)blockIdx.x * 8 + (tid >> 5);
    const int src = eidx[i];
    const int dst = eidx[NE + i];
    const float xv = xh[i*32 + c];
    atomicAdd(&o1acc[(size_t)src*32 + c], xv);
    atomicAdd(&o1acc[(size_t)dst*32 + c], xv);
    if (c == 0) {
        atomicAdd(&degb[src], 1.0f);
        atomicAdd(&degb[dst], 1.0f);
    }
}

__global__ void o1_finalize(const float* __restrict__ o1acc, const float* __restrict__ degb,
                            const float* __restrict__ attr, float* __restrict__ o1) {
    const size_t i = (size_t)blockIdx.x * 256 + threadIdx.x;
    const int n = (int)(i >> 5);
    const float d = degb[n];
    const float binv = d > 0.f ? 1.0f / d : 0.0f;
    o1[i] = o1acc[i] * binv + attr[i];
}

__global__ void edge_out(const float* __restrict__ o1, const int* __restrict__ eidx,
                         const float* __restrict__ bh, float* __restrict__ out2) {
    const size_t idx = (size_t)blockIdx.x * 256 + threadIdx.x;
    const size_t i = idx >> 5;
    const int c = (int)(idx & 31);
    const int src = eidx[i];
    const int dst = eidx[NE + i];
    out2[idx] = 0.5f * (o1[(size_t)src*32 + c] + o1[(size_t)dst*32 + c]) + bh[c];
}

extern "C" void kernel_launch(void* const* d_in, const int* in_sizes, int n_in,
                              void* d_out, int out_size, void* d_ws, size_t ws_size,
                              hipStream_t stream) {
    const float* x    = (const float*)d_in[0];
    const float* eatt = (const float*)d_in[1];
    const float* Wq   = (const float*)d_in[2];
    const float* bq   = (const float*)d_in[3];
    const float* Wk   = (const float*)d_in[4];
    const float* bk   = (const float*)d_in[5];
    const float* Wv   = (const float*)d_in[6];
    const float* bv   = (const float*)d_in[7];
    const float* We2  = (const float*)d_in[8];
    const float* be2  = (const float*)d_in[9];
    const float* We3  = (const float*)d_in[10];
    const float* be3  = (const float*)d_in[11];
    const float* Wcon = (const float*)d_in[12];
    const float* bnw  = (const float*)d_in[13];
    const float* bnb  = (const float*)d_in[14];
    const float* Wh1  = (const float*)d_in[15];
    const float* Wh2  = (const float*)d_in[16];
    const float* bh   = (const float*)d_in[17];
    const int*   eidx = (const int*)d_in[18];

    float* ws = (float*)d_ws;
    float* q     = ws + OFF_Q;
    float* k     = ws + OFF_K;
    float* v     = ws + OFF_V;
    float* ex1   = ws + OFF_EX1;
    float* ex2   = ws + OFF_EX2;
    unsigned short* Cc = (unsigned short*)(ws + OFF_CC);
    float* s1    = ws + OFF_S1;
    float* s2    = ws + OFF_S2;
    float* agg   = ws + OFF_AGG;
    unsigned short* WbT = (unsigned short*)(ws + OFF_WBT);
    float* biasb = ws + OFF_BIASB;
    float* attr  = ws + OFF_ATTR;
    float* o1    = ws + OFF_O1;
    float* xgat  = ws + OFF_XGAT;
    float* o1acc = ws + OFF_O1ACC;
    float* degb  = ws + OFF_DEGB;
    float* stats = ws + OFF_STATS;
    float* xh    = ws + OFF_XH;
    float* out0  = (float*)d_out;
    float* out1  = (float*)d_out + (size_t)NN * 32;

    // zero s1,s2,agg (contiguous)
    hipMemsetAsync(ws + OFF_S1, 0, (38288000UL - OFF_S1) * sizeof(float), stream);

    pack_w<<<129, 256, 0, stream>>>(We2, be2, We3, be3, WbT, biasb);
    qkv_kernel<<<6250, 256, 0, stream>>>(x, Wq, bq, Wk, bk, Wv, bv, q, k, v);

    // sweep 1: ea2 chunks + pass1
    for (int c = 0; c < 4; c++) {
        const long eb = (long)c * CHUNK;
        gemm_ea<<<1000, 256, 0, stream>>>(eatt + (size_t)eb * 128, WbT, biasb, Cc, 0);
        pass1<<<32000, 256, 0, stream>>>(eidx, q, k, Cc, eb, ex1, ex2, s1, s2);
    }
    // sweep 2: ea3 chunks + pass2
    for (int c = 0; c < 4; c++) {
        const long eb = (long)c * CHUNK;
        gemm_ea<<<1000, 256, 0, stream>>>(eatt + (size_t)eb * 128, WbT, biasb, Cc, 1);
        pass2<<<32000, 256, 0, stream>>>(eidx, v, Cc, eb, ex1, ex2, s1, s2, agg);
    }

    // zero o1acc, degb, stats (contiguous, region1 alias — q/k dead now)
    hipMemsetAsync(ws + OFF_O1ACC, 0, (6450064UL - OFF_O1ACC) * sizeof(float), stream);

    gemm_d128_o32<<<6250, 256, 0, stream>>>(agg, Wcon, xgat);
    bn_stats<<<256, 256, 0, stream>>>(xgat, stats);
    bn_gelu<<<6250, 256, 0, stream>>>(xgat, stats, bnw, bnb, out0);

    gemm_d128_o32<<<32000, 256, 0, stream>>>(eatt, Wh1, xh);
    gemm_d128_o32<<<6250, 256, 0, stream>>>(x, Wh2, attr);
    hyper_scatter<<<32000, 256, 0, stream>>>(xh, eidx, o1acc, degb);
    o1_finalize<<<6250, 256, 0, stream>>>(o1acc, degb, attr, o1);
    edge_out<<<32000, 256, 0, stream>>>(o1, eidx, bh, out1);
}